// Round 6
// baseline (1454.616 us; speedup 1.0000x reference)
//
#include <hip/hip_runtime.h>

typedef float f32x4 __attribute__((ext_vector_type(4)));
typedef float f32x2 __attribute__((ext_vector_type(2)));

constexpr int BKT_SHIFT = 7;     // 128 nodes per bucket
constexpr int NBKT_PAD  = 1024;  // padded bucket count (real: ceil(N/128) = 782)
constexpr int CHUNK     = 8192;  // edges per partition block
constexpr int MAXSEG    = 6144;  // LDS staging capacity per bucket (mean ~4096)

// ---- K1: per-chunk bucket histogram (LDS atomics only) ----
__global__ __launch_bounds__(256) void k1_hist(const int* __restrict__ dst,
                                               int* __restrict__ Hist, int ne) {
    __shared__ int lh[NBKT_PAD];
    for (int i = threadIdx.x; i < NBKT_PAD; i += 256) lh[i] = 0;
    __syncthreads();
    int base = blockIdx.x * CHUNK;
    int lim = min(CHUNK, ne - base);
    for (int i = threadIdx.x; i < lim; i += 256)
        atomicAdd(&lh[dst[base + i] >> BKT_SHIFT], 1);
    __syncthreads();
    for (int i = threadIdx.x; i < NBKT_PAD; i += 256)
        Hist[(size_t)blockIdx.x * NBKT_PAD + i] = lh[i];
}

// ---- K2a: per-bucket totals (8 blocks x 128 threads, bucket = global tid) ----
__global__ __launch_bounds__(128) void k2a_sum(const int* __restrict__ Hist,
                                               int* __restrict__ bucketTot, int nblk) {
    int b = blockIdx.x * 128 + threadIdx.x;
    int tot = 0;
    int blk = 0;
    for (; blk + 4 <= nblk; blk += 4)
        tot += Hist[(size_t)blk * NBKT_PAD + b] +
               Hist[(size_t)(blk + 1) * NBKT_PAD + b] +
               Hist[(size_t)(blk + 2) * NBKT_PAD + b] +
               Hist[(size_t)(blk + 3) * NBKT_PAD + b];
    for (; blk < nblk; ++blk) tot += Hist[(size_t)blk * NBKT_PAD + b];
    bucketTot[b] = tot;
}

// ---- K2b: single block scan of 1024 bucket totals -> bktBase ----
__global__ __launch_bounds__(1024) void k2b_scan(const int* __restrict__ bucketTot,
                                                 int* __restrict__ bktBase,
                                                 int* __restrict__ row_ptrN) {
    __shared__ int wsums[16];
    int t = threadIdx.x, wave = t >> 6, lane = t & 63;
    int tot = bucketTot[t];
    int x = tot;
    #pragma unroll
    for (int off = 1; off < 64; off <<= 1) {
        int y = __shfl_up(x, off, 64);
        if (lane >= off) x += y;
    }
    if (lane == 63) wsums[wave] = x;
    __syncthreads();
    if (t < 16) {
        int w = wsums[t];
        #pragma unroll
        for (int off = 1; off < 16; off <<= 1) {
            int y = __shfl_up(w, off, 64);
            if (t >= off) w += y;
        }
        wsums[t] = w;
    }
    __syncthreads();
    int excl = (wave ? wsums[wave - 1] : 0) + (x - tot);
    bktBase[t] = excl;
    if (t == 1023) { bktBase[1024] = excl + tot; *row_ptrN = excl + tot; }
}

// ---- K2c: rewrite Hist to absolute scatter offsets (per-bucket running prefix) ----
__global__ __launch_bounds__(128) void k2c_rewrite(int* __restrict__ Hist,
                                                   const int* __restrict__ bktBase, int nblk) {
    int b = blockIdx.x * 128 + threadIdx.x;
    int run = bktBase[b];
    for (int blk = 0; blk < nblk; ++blk) {
        size_t idx = (size_t)blk * NBKT_PAD + b;
        int v = Hist[idx];
        Hist[idx] = run;
        run += v;
    }
}

// ---- K3: partition edges into bucket streams (LDS cursors, no global atomics) ----
__global__ __launch_bounds__(256) void k3_partition(const int* __restrict__ src,
                                                    const int* __restrict__ dst,
                                                    const int* __restrict__ Hist,
                                                    int2* __restrict__ es, int ne) {
    __shared__ int cur[NBKT_PAD];
    for (int i = threadIdx.x; i < NBKT_PAD; i += 256)
        cur[i] = Hist[(size_t)blockIdx.x * NBKT_PAD + i];
    __syncthreads();
    int base = blockIdx.x * CHUNK;
    int lim = min(CHUNK, ne - base);
    for (int i = threadIdx.x; i < lim; i += 256) {
        int d = dst[base + i];
        int s = src[base + i];
        int pos = atomicAdd(&cur[d >> BKT_SHIFT], 1);
        es[pos] = make_int2(s, d);
    }
}

// ---- K4: per-bucket fine CSR (counting sort over 128 nodes) + row_ptr + dinv ----
__global__ __launch_bounds__(256) void k4_csr(const int2* __restrict__ es,
                                              const int* __restrict__ bktBase,
                                              int* __restrict__ col_idx,
                                              int* __restrict__ row_ptr,
                                              float* __restrict__ dinv, int n) {
    __shared__ int hist[128];
    __shared__ int rbase[128];
    __shared__ int cur[128];
    __shared__ int stage[MAXSEG];
    int b = blockIdx.x;
    int segs = bktBase[b], sege = bktBase[b + 1];
    int seglen = sege - segs;
    int node0 = b << BKT_SHIFT;
    int nloc = min(128, n - node0);
    int t = threadIdx.x;
    if (t < 128) hist[t] = 0;
    __syncthreads();
    for (int i = t; i < seglen; i += 256)
        atomicAdd(&hist[es[segs + i].y - node0], 1);
    __syncthreads();
    if (t < 64) {  // wave 0: exclusive scan of 128 counters, 2 per lane
        int a0 = hist[2 * t], a1 = hist[2 * t + 1];
        int pair = a0 + a1;
        int x = pair;
        #pragma unroll
        for (int off = 1; off < 64; off <<= 1) {
            int y = __shfl_up(x, off, 64);
            if (t >= off) x += y;
        }
        int excl = x - pair;
        rbase[2 * t] = excl;       rbase[2 * t + 1] = excl + a0;
        cur[2 * t]   = excl;       cur[2 * t + 1]   = excl + a0;
    }
    __syncthreads();
    if (seglen <= MAXSEG) {
        for (int i = t; i < seglen; i += 256) {
            int2 e = es[segs + i];
            int pos = atomicAdd(&cur[e.y - node0], 1);
            stage[pos] = e.x;
        }
        __syncthreads();
        for (int i = t; i < seglen; i += 256)
            col_idx[segs + i] = stage[i];
    } else {  // overflow fallback: direct (rare with uniform graphs)
        for (int i = t; i < seglen; i += 256) {
            int2 e = es[segs + i];
            int pos = atomicAdd(&cur[e.y - node0], 1);
            col_idx[segs + pos] = e.x;
        }
    }
    if (t < nloc) {
        row_ptr[node0 + t] = segs + rbase[t];
        dinv[node0 + t] = 1.0f / sqrtf((float)(hist[t] + 1));  // deg incl self loop
    }
}

// ---------------- row-tiled dense GEMM: Y = X @ W ----------------
// EPI: 0 -> *dinv[row], 1 -> tanh(+bias).
template<int K, int FOUT, int EPI, int RT>
__global__ __launch_bounds__(256) void gemm_tiled(const float* __restrict__ X,
        const float* __restrict__ W, const float* __restrict__ bias,
        const float* __restrict__ dinv, float* __restrict__ Y, int nrows) {
    __shared__ float Wl[K * FOUT];
    __shared__ float Xs[RT * K];
    int tid = threadIdx.x;
    const float4* Wg4 = (const float4*)W;
    float4* Wl4 = (float4*)Wl;
    for (int i = tid; i < K * FOUT / 4; i += 256) Wl4[i] = Wg4[i];
    int row0 = blockIdx.x * RT;
    int nr = min(RT, nrows - row0);
    {
        const float4* Xg4 = (const float4*)(X + (size_t)row0 * K);
        float4* Xs4 = (float4*)Xs;
        int lim = nr * (K / 4);
        for (int i = tid; i < lim; i += 256) Xs4[i] = Xg4[i];
    }
    __syncthreads();

    constexpr int NG  = 256 / FOUT;   // groups per block
    constexpr int RPT = RT / NG;      // rows per thread
    int c = tid & (FOUT - 1);
    int g = tid / FOUT;
    int rbase = g * RPT;
    float acc[RPT];
    #pragma unroll
    for (int i = 0; i < RPT; ++i) acc[i] = 0.f;
    #pragma unroll 4
    for (int k = 0; k < K; ++k) {
        float wv = Wl[k * FOUT + c];
        #pragma unroll
        for (int i = 0; i < RPT; ++i)
            acc[i] = fmaf(Xs[(rbase + i) * K + k], wv, acc[i]);
    }
    float bv = (EPI == 1) ? bias[c] : 0.f;
    #pragma unroll
    for (int i = 0; i < RPT; ++i) {
        int r = row0 + rbase + i;
        if (r < nrows) {
            float v = acc[i];
            if (EPI == 0) v *= dinv[r];
            else          v = tanhf(v + bv);
            Y[(size_t)r * FOUT + c] = v;
        }
    }
}

// ---------------- fused head: h5=tanh(X@W5+b5); 256->24->18->12 tanh chain ----------------
__global__ __launch_bounds__(256) void head_kernel(const float* __restrict__ X,
        const float* __restrict__ W5, const float* __restrict__ b5,
        const float* __restrict__ Wl1, const float* __restrict__ bl1,
        const float* __restrict__ Wl2, const float* __restrict__ bl2,
        const float* __restrict__ Wl3, const float* __restrict__ bl3,
        float* __restrict__ Y, int nrows) {
    constexpr int RT = 16;
    __shared__ float W5s[32 * 256];   // 32 KB
    __shared__ float W1s[256 * 24];   // 24 KB
    __shared__ float W2s[24 * 18];
    __shared__ float W3s[18 * 12];
    __shared__ float b1s[24], b2s[18], b3s[12];
    __shared__ float Xs[RT * 32];
    __shared__ float H5[RT * 257];    // pad 257: phase-B reads stride-257 -> distinct banks
    __shared__ float H24[RT * 25];
    __shared__ float H18[RT * 19];
    int tid = threadIdx.x;
    for (int i = tid; i < 32 * 256 / 4; i += 256) ((float4*)W5s)[i] = ((const float4*)W5)[i];
    for (int i = tid; i < 256 * 24 / 4; i += 256) ((float4*)W1s)[i] = ((const float4*)Wl1)[i];
    for (int i = tid; i < 432; i += 256) W2s[i] = Wl2[i];
    for (int i = tid; i < 216; i += 256) W3s[i] = Wl3[i];
    if (tid < 24) b1s[tid] = bl1[tid];
    if (tid < 18) b2s[tid] = bl2[tid];
    if (tid < 12) b3s[tid] = bl3[tid];
    float b5r = b5[tid];              // per-thread bias, keep out of LDS
    int row0 = blockIdx.x * RT;
    int nr = min(RT, nrows - row0);
    {
        const float4* Xg4 = (const float4*)(X + (size_t)row0 * 32);
        for (int i = tid; i < nr * 8; i += 256) ((float4*)Xs)[i] = Xg4[i];
    }
    __syncthreads();
    // Phase A: H5[r][c] = tanh(sum_k Xs[r][k] * W5[k][c] + b5[c]); c = tid
    {
        float acc[RT];
        #pragma unroll
        for (int r = 0; r < RT; ++r) acc[r] = 0.f;
        #pragma unroll 4
        for (int k = 0; k < 32; ++k) {
            float wv = W5s[k * 256 + tid];
            #pragma unroll
            for (int r = 0; r < RT; ++r)
                acc[r] = fmaf(Xs[r * 32 + k], wv, acc[r]);
        }
        #pragma unroll
        for (int r = 0; r < RT; ++r) H5[r * 257 + tid] = tanhf(acc[r] + b5r);
    }
    __syncthreads();
    // Phase B: 256 -> 24
    for (int o = tid; o < RT * 24; o += 256) {
        int r = o / 24, c = o - r * 24;
        float acc = 0.f;
        #pragma unroll 4
        for (int k = 0; k < 256; ++k) acc = fmaf(H5[r * 257 + k], W1s[k * 24 + c], acc);
        H24[r * 25 + c] = tanhf(acc + b1s[c]);
    }
    __syncthreads();
    // Phase C: 24 -> 18
    for (int o = tid; o < RT * 18; o += 256) {
        int r = o / 18, c = o - r * 18;
        float acc = 0.f;
        #pragma unroll
        for (int k = 0; k < 24; ++k) acc = fmaf(H24[r * 25 + k], W2s[k * 18 + c], acc);
        H18[r * 19 + c] = tanhf(acc + b2s[c]);
    }
    __syncthreads();
    // Phase D: 18 -> 12, write
    for (int o = tid; o < RT * 12; o += 256) {
        int r = o / 12, c = o - r * 12;
        float acc = 0.f;
        #pragma unroll
        for (int k = 0; k < 18; ++k) acc = fmaf(H18[r * 19 + k], W3s[k * 12 + c], acc);
        if (r < nr) Y[(size_t)(row0 + r) * 12 + c] = tanhf(acc + b3s[c]);
    }
}

// ---------------- CSR aggregation (vectorized) ----------------
// POSTSCALE: multiply final (post-tanh) row by dinv[node] (feeds next layer's
// aggregate-first associativity without a separate mul_dinv pass).
template<int F, bool FINAL, bool POSTSCALE>
__global__ __launch_bounds__(256) void aggregate_kernel(const float* __restrict__ Z,
        const int* __restrict__ row_ptr, const int* __restrict__ col_idx,
        const float* __restrict__ dinv, const float* __restrict__ bias,
        float* __restrict__ out, int n) {
    constexpr int LPR = F / 4;      // lanes per neighbor row (16 or 8)
    constexpr int G   = 64 / LPR;   // neighbors per step (4 or 8)
    int tid = threadIdx.x;
    int wave = tid >> 6, lane = tid & 63;
    int g = lane / LPR;
    int c = lane - g * LPR;
    int node = blockIdx.x * 4 + wave;
    if (node >= n) return;
    int start = row_ptr[node];
    int end   = row_ptr[node + 1];
    float4 acc = make_float4(0.f, 0.f, 0.f, 0.f);
    int wbase = start;
    int iv = (wbase + lane < end) ? col_idx[wbase + lane] : 0;
    #pragma unroll 2
    for (int base = start; base < end; base += G) {
        if (base - wbase == 64) {
            wbase += 64;
            iv = (wbase + lane < end) ? col_idx[wbase + lane] : 0;
        }
        int s = __shfl(iv, (base - wbase) + g, 64);
        if (base + g < end) {
            const float4 v = *(const float4*)(Z + (size_t)s * F + c * 4);
            acc.x += v.x; acc.y += v.y; acc.z += v.z; acc.w += v.w;
        }
    }
    #pragma unroll
    for (int off = LPR; off < 64; off <<= 1) {
        acc.x += __shfl_xor(acc.x, off, 64);
        acc.y += __shfl_xor(acc.y, off, 64);
        acc.z += __shfl_xor(acc.z, off, 64);
        acc.w += __shfl_xor(acc.w, off, 64);
    }
    if (g == 0) {
        const float4 sv = *(const float4*)(Z + (size_t)node * F + c * 4);
        float di = dinv[node];
        float4 r;
        r.x = di * (acc.x + sv.x);
        r.y = di * (acc.y + sv.y);
        r.z = di * (acc.z + sv.z);
        r.w = di * (acc.w + sv.w);
        if (FINAL) {
            const float4 bv = *(const float4*)(bias + c * 4);
            r.x = tanhf(r.x + bv.x);
            r.y = tanhf(r.y + bv.y);
            r.z = tanhf(r.z + bv.z);
            r.w = tanhf(r.w + bv.w);
        }
        if (POSTSCALE) { r.x *= di; r.y *= di; r.z *= di; r.w *= di; }
        *(float4*)(out + (size_t)node * F + c * 4) = r;
    }
}

// ---------------- final: e = [h[src], h[dst]], out = e @ Wc + bc ----------------
__global__ __launch_bounds__(256) void edge_kernel(const int* __restrict__ src,
        const int* __restrict__ dst, const float* __restrict__ h,
        const float* __restrict__ Wc, const float* __restrict__ bc,
        float* __restrict__ out, float* __restrict__ efeat, int ne) {
    __shared__ float Wl[144];
    __shared__ float bl[6];
    if (threadIdx.x < 144) Wl[threadIdx.x] = Wc[threadIdx.x];
    if (threadIdx.x < 6) bl[threadIdx.x] = bc[threadIdx.x];
    __syncthreads();
    int e = blockIdx.x * 256 + threadIdx.x;
    if (e >= ne) return;
    int s = src[e], d = dst[e];
    const float* hs = h + (size_t)s * 12;
    const float* hd = h + (size_t)d * 12;
    f32x4 v0 = *(const f32x4*)(hs + 0);
    f32x4 v1 = *(const f32x4*)(hs + 4);
    f32x4 v2 = *(const f32x4*)(hs + 8);
    f32x4 v3 = *(const f32x4*)(hd + 0);
    f32x4 v4 = *(const f32x4*)(hd + 4);
    f32x4 v5 = *(const f32x4*)(hd + 8);
    float v[24];
    *(f32x4*)(v + 0)  = v0; *(f32x4*)(v + 4)  = v1; *(f32x4*)(v + 8)  = v2;
    *(f32x4*)(v + 12) = v3; *(f32x4*)(v + 16) = v4; *(f32x4*)(v + 20) = v5;
    f32x4* ef4 = (f32x4*)(efeat + (size_t)e * 24);
    __builtin_nontemporal_store(v0, ef4 + 0);
    __builtin_nontemporal_store(v1, ef4 + 1);
    __builtin_nontemporal_store(v2, ef4 + 2);
    __builtin_nontemporal_store(v3, ef4 + 3);
    __builtin_nontemporal_store(v4, ef4 + 4);
    __builtin_nontemporal_store(v5, ef4 + 5);
    float o[6];
    #pragma unroll
    for (int c = 0; c < 6; ++c) {
        float acc = bl[c];
        #pragma unroll
        for (int k = 0; k < 24; ++k) acc = fmaf(v[k], Wl[k * 6 + c], acc);
        o[c] = acc;
    }
    f32x2* o2 = (f32x2*)(out + (size_t)e * 6);
    f32x2 p0; p0.x = o[0]; p0.y = o[1];
    f32x2 p1; p1.x = o[2]; p1.y = o[3];
    f32x2 p2; p2.x = o[4]; p2.y = o[5];
    __builtin_nontemporal_store(p0, o2 + 0);
    __builtin_nontemporal_store(p1, o2 + 1);
    __builtin_nontemporal_store(p2, o2 + 2);
}

extern "C" void kernel_launch(void* const* d_in, const int* in_sizes, int n_in,
                              void* d_out, int out_size, void* d_ws, size_t ws_size,
                              hipStream_t stream) {
    const int N = in_sizes[0] / 128;
    const int E = in_sizes[1] / 2;

    const float* x   = (const float*)d_in[0];
    const int*   ei  = (const int*)d_in[1];
    const int*   srcE = ei;
    const int*   dstE = ei + E;
    const float* W1 = (const float*)d_in[3];  const float* b1 = (const float*)d_in[4];
    const float* W2 = (const float*)d_in[5];  const float* b2 = (const float*)d_in[6];
    const float* W3 = (const float*)d_in[7];  const float* b3 = (const float*)d_in[8];
    const float* W4 = (const float*)d_in[9];  const float* b4 = (const float*)d_in[10];
    const float* W5 = (const float*)d_in[11]; const float* b5 = (const float*)d_in[12];
    const float* Wl1 = (const float*)d_in[13]; const float* bl1 = (const float*)d_in[14];
    const float* Wl2 = (const float*)d_in[15]; const float* bl2 = (const float*)d_in[16];
    const float* Wl3 = (const float*)d_in[17]; const float* bl3 = (const float*)d_in[18];
    const float* Wc  = (const float*)d_in[19]; const float* bc  = (const float*)d_in[20];

    // ---- workspace (small persistent arrays) ----
    char* ws = (char*)d_ws;
    size_t off = 0;
    auto take = [&](size_t bytes) -> char* {
        char* p = ws + off;
        off += (bytes + 255) & ~(size_t)255;
        return p;
    };
    int*   row_ptr   = (int*)take((size_t)(N + 1) * 4);
    float* dinv      = (float*)take((size_t)N * 4);
    int*   col_idx   = (int*)take((size_t)E * 4);
    float* h8        = (float*)take((size_t)N * 12 * 4);
    int*   bktBase   = (int*)take((size_t)(NBKT_PAD + 1) * 4);
    int*   bucketTot = (int*)take((size_t)NBKT_PAD * 4);

    // big/transient buffers inside d_out's e-region (dead until edge_kernel overwrites it)
    float* outbuf  = (float*)d_out;
    float* eregion = outbuf + (size_t)E * 6;
    int2* es  = (int2*)eregion;                  // E * 8B (CSR transient)
    int*  Hist = (int*)(es + E);                 // nblk * 1024 * 4B (CSR transient)
    float* bufZ = eregion;                       // up to N*64 (live after CSR build)
    float* bufH = eregion + (size_t)N * 64;      // up to N*64

    int gE = (E + 255) / 256;
    int gAgg = (N + 3) / 4;
    int nblk = (E + CHUNK - 1) / CHUNK;
    int nbkt = (N + 127) >> BKT_SHIFT;
    auto tiles = [&](int rt) { return (N + rt - 1) / rt; };

    // ---- CSR build (no global atomics) ----
    k1_hist<<<nblk, 256, 0, stream>>>(dstE, Hist, E);
    k2a_sum<<<NBKT_PAD / 128, 128, 0, stream>>>(Hist, bucketTot, nblk);
    k2b_scan<<<1, 1024, 0, stream>>>(bucketTot, bktBase, row_ptr + N);
    k2c_rewrite<<<NBKT_PAD / 128, 128, 0, stream>>>(Hist, bktBase, nblk);
    k3_partition<<<nblk, 256, 0, stream>>>(srcE, dstE, Hist, es, E);
    k4_csr<<<nbkt, 256, 0, stream>>>(es, bktBase, col_idx, row_ptr, dinv, N);

    // ---- layer 1: 128 -> 64 ----
    gemm_tiled<128, 64, 0, 16><<<tiles(16), 256, 0, stream>>>(x, W1, nullptr, dinv, bufZ, N);
    aggregate_kernel<64, true, false><<<gAgg, 256, 0, stream>>>(bufZ, row_ptr, col_idx, dinv, b1, bufH, N);
    // ---- layer 2: 64 -> 64 ----
    gemm_tiled<64, 64, 0, 16><<<tiles(16), 256, 0, stream>>>(bufH, W2, nullptr, dinv, bufZ, N);
    aggregate_kernel<64, true, false><<<gAgg, 256, 0, stream>>>(bufZ, row_ptr, col_idx, dinv, b2, bufH, N);
    // ---- layer 3: 64 -> 32 ----
    gemm_tiled<64, 32, 0, 16><<<tiles(16), 256, 0, stream>>>(bufH, W3, nullptr, dinv, bufZ, N);
    aggregate_kernel<32, true, false><<<gAgg, 256, 0, stream>>>(bufZ, row_ptr, col_idx, dinv, b3, bufH, N);
    // ---- layer 4: 32 -> 32, POSTSCALE folds the next layer's dinv pre-multiply ----
    gemm_tiled<32, 32, 0, 16><<<tiles(16), 256, 0, stream>>>(bufH, W4, nullptr, dinv, bufZ, N);
    aggregate_kernel<32, true, true><<<gAgg, 256, 0, stream>>>(bufZ, row_ptr, col_idx, dinv, b4, bufH, N);
    // ---- layer 5 aggregate (input already h4*dinv) ----
    aggregate_kernel<32, false, false><<<gAgg, 256, 0, stream>>>(bufH, row_ptr, col_idx, dinv, nullptr, bufZ, N);
    // ---- fused head: 32->256 tanh, 256->24->18->12 tanh chain ----
    head_kernel<<<tiles(16), 256, 0, stream>>>(bufZ, W5, b5, Wl1, bl1, Wl2, bl2, Wl3, bl3, h8, N);
    // ---- edge output ----
    edge_kernel<<<gE, 256, 0, stream>>>(srcE, dstE, h8, Wc, bc, outbuf, eregion, E);
}

// Round 7
// 1017.213 us; speedup vs baseline: 1.4300x; 1.4300x over previous
//
#include <hip/hip_runtime.h>

typedef float f32x4 __attribute__((ext_vector_type(4)));
typedef float f32x2 __attribute__((ext_vector_type(2)));

constexpr int BKT_SHIFT = 7;     // 128 nodes per bucket
constexpr int NBKT_PAD  = 1024;  // padded bucket count (real: ceil(N/128) = 782)
constexpr int CHUNK     = 8192;  // edges per partition block
constexpr int MAXSEG    = 6144;  // LDS staging capacity per bucket (mean ~4096)

// ---- K1: per-chunk bucket histogram (LDS atomics only) ----
__global__ __launch_bounds__(256) void k1_hist(const int* __restrict__ dst,
                                               int* __restrict__ Hist, int ne) {
    __shared__ int lh[NBKT_PAD];
    for (int i = threadIdx.x; i < NBKT_PAD; i += 256) lh[i] = 0;
    __syncthreads();
    int base = blockIdx.x * CHUNK;
    int lim = min(CHUNK, ne - base);
    for (int i = threadIdx.x; i < lim; i += 256)
        atomicAdd(&lh[dst[base + i] >> BKT_SHIFT], 1);
    __syncthreads();
    for (int i = threadIdx.x; i < NBKT_PAD; i += 256)
        Hist[(size_t)blockIdx.x * NBKT_PAD + i] = lh[i];
}

// ---- K2a: per-bucket totals (8 blocks x 128 threads, bucket = global tid) ----
__global__ __launch_bounds__(128) void k2a_sum(const int* __restrict__ Hist,
                                               int* __restrict__ bucketTot, int nblk) {
    int b = blockIdx.x * 128 + threadIdx.x;
    int tot = 0;
    int blk = 0;
    for (; blk + 4 <= nblk; blk += 4)
        tot += Hist[(size_t)blk * NBKT_PAD + b] +
               Hist[(size_t)(blk + 1) * NBKT_PAD + b] +
               Hist[(size_t)(blk + 2) * NBKT_PAD + b] +
               Hist[(size_t)(blk + 3) * NBKT_PAD + b];
    for (; blk < nblk; ++blk) tot += Hist[(size_t)blk * NBKT_PAD + b];
    bucketTot[b] = tot;
}

// ---- K2b: single block scan of 1024 bucket totals -> bktBase ----
__global__ __launch_bounds__(1024) void k2b_scan(const int* __restrict__ bucketTot,
                                                 int* __restrict__ bktBase,
                                                 int* __restrict__ row_ptrN) {
    __shared__ int wsums[16];
    int t = threadIdx.x, wave = t >> 6, lane = t & 63;
    int tot = bucketTot[t];
    int x = tot;
    #pragma unroll
    for (int off = 1; off < 64; off <<= 1) {
        int y = __shfl_up(x, off, 64);
        if (lane >= off) x += y;
    }
    if (lane == 63) wsums[wave] = x;
    __syncthreads();
    if (t < 16) {
        int w = wsums[t];
        #pragma unroll
        for (int off = 1; off < 16; off <<= 1) {
            int y = __shfl_up(w, off, 64);
            if (t >= off) w += y;
        }
        wsums[t] = w;
    }
    __syncthreads();
    int excl = (wave ? wsums[wave - 1] : 0) + (x - tot);
    bktBase[t] = excl;
    if (t == 1023) { bktBase[1024] = excl + tot; *row_ptrN = excl + tot; }
}

// ---- K2c: rewrite Hist to absolute scatter offsets (per-bucket running prefix) ----
__global__ __launch_bounds__(128) void k2c_rewrite(int* __restrict__ Hist,
                                                   const int* __restrict__ bktBase, int nblk) {
    int b = blockIdx.x * 128 + threadIdx.x;
    int run = bktBase[b];
    for (int blk = 0; blk < nblk; ++blk) {
        size_t idx = (size_t)blk * NBKT_PAD + b;
        int v = Hist[idx];
        Hist[idx] = run;
        run += v;
    }
}

// ---- K3: partition edges into bucket streams (LDS cursors, no global atomics) ----
__global__ __launch_bounds__(256) void k3_partition(const int* __restrict__ src,
                                                    const int* __restrict__ dst,
                                                    const int* __restrict__ Hist,
                                                    int2* __restrict__ es, int ne) {
    __shared__ int cur[NBKT_PAD];
    for (int i = threadIdx.x; i < NBKT_PAD; i += 256)
        cur[i] = Hist[(size_t)blockIdx.x * NBKT_PAD + i];
    __syncthreads();
    int base = blockIdx.x * CHUNK;
    int lim = min(CHUNK, ne - base);
    for (int i = threadIdx.x; i < lim; i += 256) {
        int d = dst[base + i];
        int s = src[base + i];
        int pos = atomicAdd(&cur[d >> BKT_SHIFT], 1);
        es[pos] = make_int2(s, d);
    }
}

// ---- K4: per-bucket fine CSR (counting sort over 128 nodes) + row_ptr + dinv ----
__global__ __launch_bounds__(256) void k4_csr(const int2* __restrict__ es,
                                              const int* __restrict__ bktBase,
                                              int* __restrict__ col_idx,
                                              int* __restrict__ row_ptr,
                                              float* __restrict__ dinv, int n) {
    __shared__ int hist[128];
    __shared__ int rbase[128];
    __shared__ int cur[128];
    __shared__ int stage[MAXSEG];
    int b = blockIdx.x;
    int segs = bktBase[b], sege = bktBase[b + 1];
    int seglen = sege - segs;
    int node0 = b << BKT_SHIFT;
    int nloc = min(128, n - node0);
    int t = threadIdx.x;
    if (t < 128) hist[t] = 0;
    __syncthreads();
    for (int i = t; i < seglen; i += 256)
        atomicAdd(&hist[es[segs + i].y - node0], 1);
    __syncthreads();
    if (t < 64) {  // wave 0: exclusive scan of 128 counters, 2 per lane
        int a0 = hist[2 * t], a1 = hist[2 * t + 1];
        int pair = a0 + a1;
        int x = pair;
        #pragma unroll
        for (int off = 1; off < 64; off <<= 1) {
            int y = __shfl_up(x, off, 64);
            if (t >= off) x += y;
        }
        int excl = x - pair;
        rbase[2 * t] = excl;       rbase[2 * t + 1] = excl + a0;
        cur[2 * t]   = excl;       cur[2 * t + 1]   = excl + a0;
    }
    __syncthreads();
    if (seglen <= MAXSEG) {
        for (int i = t; i < seglen; i += 256) {
            int2 e = es[segs + i];
            int pos = atomicAdd(&cur[e.y - node0], 1);
            stage[pos] = e.x;
        }
        __syncthreads();
        for (int i = t; i < seglen; i += 256)
            col_idx[segs + i] = stage[i];
    } else {  // overflow fallback: direct (rare with uniform graphs)
        for (int i = t; i < seglen; i += 256) {
            int2 e = es[segs + i];
            int pos = atomicAdd(&cur[e.y - node0], 1);
            col_idx[segs + pos] = e.x;
        }
    }
    if (t < nloc) {
        row_ptr[node0 + t] = segs + rbase[t];
        dinv[node0 + t] = 1.0f / sqrtf((float)(hist[t] + 1));  // deg incl self loop
    }
}

// ---------------- row-tiled dense GEMM: Y = X @ W ----------------
// EPI: 0 -> *dinv[row], 1 -> tanh(+bias).
template<int K, int FOUT, int EPI, int RT>
__global__ __launch_bounds__(256) void gemm_tiled(const float* __restrict__ X,
        const float* __restrict__ W, const float* __restrict__ bias,
        const float* __restrict__ dinv, float* __restrict__ Y, int nrows) {
    __shared__ float Wl[K * FOUT];
    __shared__ float Xs[RT * K];
    int tid = threadIdx.x;
    const float4* Wg4 = (const float4*)W;
    float4* Wl4 = (float4*)Wl;
    for (int i = tid; i < K * FOUT / 4; i += 256) Wl4[i] = Wg4[i];
    int row0 = blockIdx.x * RT;
    int nr = min(RT, nrows - row0);
    {
        const float4* Xg4 = (const float4*)(X + (size_t)row0 * K);
        float4* Xs4 = (float4*)Xs;
        int lim = nr * (K / 4);
        for (int i = tid; i < lim; i += 256) Xs4[i] = Xg4[i];
    }
    __syncthreads();

    constexpr int NG  = 256 / FOUT;   // groups per block
    constexpr int RPT = RT / NG;      // rows per thread
    int c = tid & (FOUT - 1);
    int g = tid / FOUT;
    int rbase = g * RPT;
    float acc[RPT];
    #pragma unroll
    for (int i = 0; i < RPT; ++i) acc[i] = 0.f;
    #pragma unroll 4
    for (int k = 0; k < K; ++k) {
        float wv = Wl[k * FOUT + c];
        #pragma unroll
        for (int i = 0; i < RPT; ++i)
            acc[i] = fmaf(Xs[(rbase + i) * K + k], wv, acc[i]);
    }
    float bv = (EPI == 1) ? bias[c] : 0.f;
    #pragma unroll
    for (int i = 0; i < RPT; ++i) {
        int r = row0 + rbase + i;
        if (r < nrows) {
            float v = acc[i];
            if (EPI == 0) v *= dinv[r];
            else          v = tanhf(v + bv);
            Y[(size_t)r * FOUT + c] = v;
        }
    }
}

// ---------------- fused head: h5=tanh(X@W5+b5); 256->24->18->12 tanh chain ----------------
__global__ __launch_bounds__(256) void head_kernel(const float* __restrict__ X,
        const float* __restrict__ W5, const float* __restrict__ b5,
        const float* __restrict__ Wl1, const float* __restrict__ bl1,
        const float* __restrict__ Wl2, const float* __restrict__ bl2,
        const float* __restrict__ Wl3, const float* __restrict__ bl3,
        float* __restrict__ Y, int nrows) {
    constexpr int RT = 16;
    __shared__ float W5s[32 * 256];   // 32 KB
    __shared__ float W1s[256 * 24];   // 24 KB
    __shared__ float W2s[24 * 18];
    __shared__ float W3s[18 * 12];
    __shared__ float b1s[24], b2s[18], b3s[12];
    __shared__ float Xs[RT * 32];
    __shared__ float H5[RT * 257];    // pad 257: phase-B reads stride-257 -> distinct banks
    __shared__ float H24[RT * 25];
    __shared__ float H18[RT * 19];
    int tid = threadIdx.x;
    for (int i = tid; i < 32 * 256 / 4; i += 256) ((float4*)W5s)[i] = ((const float4*)W5)[i];
    for (int i = tid; i < 256 * 24 / 4; i += 256) ((float4*)W1s)[i] = ((const float4*)Wl1)[i];
    for (int i = tid; i < 432; i += 256) W2s[i] = Wl2[i];
    for (int i = tid; i < 216; i += 256) W3s[i] = Wl3[i];
    if (tid < 24) b1s[tid] = bl1[tid];
    if (tid < 18) b2s[tid] = bl2[tid];
    if (tid < 12) b3s[tid] = bl3[tid];
    float b5r = b5[tid];              // per-thread bias, keep out of LDS
    int row0 = blockIdx.x * RT;
    int nr = min(RT, nrows - row0);
    {
        const float4* Xg4 = (const float4*)(X + (size_t)row0 * 32);
        for (int i = tid; i < nr * 8; i += 256) ((float4*)Xs)[i] = Xg4[i];
    }
    __syncthreads();
    // Phase A: H5[r][c] = tanh(sum_k Xs[r][k] * W5[k][c] + b5[c]); c = tid
    {
        float acc[RT];
        #pragma unroll
        for (int r = 0; r < RT; ++r) acc[r] = 0.f;
        #pragma unroll 4
        for (int k = 0; k < 32; ++k) {
            float wv = W5s[k * 256 + tid];
            #pragma unroll
            for (int r = 0; r < RT; ++r)
                acc[r] = fmaf(Xs[r * 32 + k], wv, acc[r]);
        }
        #pragma unroll
        for (int r = 0; r < RT; ++r) H5[r * 257 + tid] = tanhf(acc[r] + b5r);
    }
    __syncthreads();
    // Phase B: 256 -> 24
    for (int o = tid; o < RT * 24; o += 256) {
        int r = o / 24, c = o - r * 24;
        float acc = 0.f;
        #pragma unroll 4
        for (int k = 0; k < 256; ++k) acc = fmaf(H5[r * 257 + k], W1s[k * 24 + c], acc);
        H24[r * 25 + c] = tanhf(acc + b1s[c]);
    }
    __syncthreads();
    // Phase C: 24 -> 18
    for (int o = tid; o < RT * 18; o += 256) {
        int r = o / 18, c = o - r * 18;
        float acc = 0.f;
        #pragma unroll
        for (int k = 0; k < 24; ++k) acc = fmaf(H24[r * 25 + k], W2s[k * 18 + c], acc);
        H18[r * 19 + c] = tanhf(acc + b2s[c]);
    }
    __syncthreads();
    // Phase D: 18 -> 12, write
    for (int o = tid; o < RT * 12; o += 256) {
        int r = o / 12, c = o - r * 12;
        float acc = 0.f;
        #pragma unroll
        for (int k = 0; k < 18; ++k) acc = fmaf(H18[r * 19 + k], W3s[k * 12 + c], acc);
        if (r < nr) Y[(size_t)(row0 + r) * 12 + c] = tanhf(acc + b3s[c]);
    }
}

// ---------------- CSR aggregation (vectorized) ----------------
// POSTSCALE: multiply final (post-tanh) row by dinv[node] (feeds next layer's
// aggregate-first associativity without a separate mul_dinv pass).
template<int F, bool FINAL, bool POSTSCALE>
__global__ __launch_bounds__(256) void aggregate_kernel(const float* __restrict__ Z,
        const int* __restrict__ row_ptr, const int* __restrict__ col_idx,
        const float* __restrict__ dinv, const float* __restrict__ bias,
        float* __restrict__ out, int n) {
    constexpr int LPR = F / 4;      // lanes per neighbor row (16 or 8)
    constexpr int G   = 64 / LPR;   // neighbors per step (4 or 8)
    int tid = threadIdx.x;
    int wave = tid >> 6, lane = tid & 63;
    int g = lane / LPR;
    int c = lane - g * LPR;
    int node = blockIdx.x * 4 + wave;
    if (node >= n) return;
    int start = row_ptr[node];
    int end   = row_ptr[node + 1];
    float4 acc = make_float4(0.f, 0.f, 0.f, 0.f);
    int wbase = start;
    int iv = (wbase + lane < end) ? col_idx[wbase + lane] : 0;
    #pragma unroll 2
    for (int base = start; base < end; base += G) {
        if (base - wbase == 64) {
            wbase += 64;
            iv = (wbase + lane < end) ? col_idx[wbase + lane] : 0;
        }
        int s = __shfl(iv, (base - wbase) + g, 64);
        if (base + g < end) {
            const float4 v = *(const float4*)(Z + (size_t)s * F + c * 4);
            acc.x += v.x; acc.y += v.y; acc.z += v.z; acc.w += v.w;
        }
    }
    #pragma unroll
    for (int off = LPR; off < 64; off <<= 1) {
        acc.x += __shfl_xor(acc.x, off, 64);
        acc.y += __shfl_xor(acc.y, off, 64);
        acc.z += __shfl_xor(acc.z, off, 64);
        acc.w += __shfl_xor(acc.w, off, 64);
    }
    if (g == 0) {
        const float4 sv = *(const float4*)(Z + (size_t)node * F + c * 4);
        float di = dinv[node];
        float4 r;
        r.x = di * (acc.x + sv.x);
        r.y = di * (acc.y + sv.y);
        r.z = di * (acc.z + sv.z);
        r.w = di * (acc.w + sv.w);
        if (FINAL) {
            const float4 bv = *(const float4*)(bias + c * 4);
            r.x = tanhf(r.x + bv.x);
            r.y = tanhf(r.y + bv.y);
            r.z = tanhf(r.z + bv.z);
            r.w = tanhf(r.w + bv.w);
        }
        if (POSTSCALE) { r.x *= di; r.y *= di; r.z *= di; r.w *= di; }
        *(float4*)(out + (size_t)node * F + c * 4) = r;
    }
}

// ---------------- final: e = [h[src], h[dst]], out = e @ Wc + bc ----------------
__global__ __launch_bounds__(256) void edge_kernel(const int* __restrict__ src,
        const int* __restrict__ dst, const float* __restrict__ h,
        const float* __restrict__ Wc, const float* __restrict__ bc,
        float* __restrict__ out, float* __restrict__ efeat, int ne) {
    __shared__ float Wl[144];
    __shared__ float bl[6];
    if (threadIdx.x < 144) Wl[threadIdx.x] = Wc[threadIdx.x];
    if (threadIdx.x < 6) bl[threadIdx.x] = bc[threadIdx.x];
    __syncthreads();
    int e = blockIdx.x * 256 + threadIdx.x;
    if (e >= ne) return;
    int s = src[e], d = dst[e];
    const float* hs = h + (size_t)s * 12;
    const float* hd = h + (size_t)d * 12;
    f32x4 v0 = *(const f32x4*)(hs + 0);
    f32x4 v1 = *(const f32x4*)(hs + 4);
    f32x4 v2 = *(const f32x4*)(hs + 8);
    f32x4 v3 = *(const f32x4*)(hd + 0);
    f32x4 v4 = *(const f32x4*)(hd + 4);
    f32x4 v5 = *(const f32x4*)(hd + 8);
    float v[24];
    *(f32x4*)(v + 0)  = v0; *(f32x4*)(v + 4)  = v1; *(f32x4*)(v + 8)  = v2;
    *(f32x4*)(v + 12) = v3; *(f32x4*)(v + 16) = v4; *(f32x4*)(v + 20) = v5;
    f32x4* ef4 = (f32x4*)(efeat + (size_t)e * 24);
    ef4[0] = v0; ef4[1] = v1; ef4[2] = v2; ef4[3] = v3; ef4[4] = v4; ef4[5] = v5;
    float o[6];
    #pragma unroll
    for (int c = 0; c < 6; ++c) {
        float acc = bl[c];
        #pragma unroll
        for (int k = 0; k < 24; ++k) acc = fmaf(v[k], Wl[k * 6 + c], acc);
        o[c] = acc;
    }
    f32x2* o2 = (f32x2*)(out + (size_t)e * 6);
    f32x2 p0; p0.x = o[0]; p0.y = o[1];
    f32x2 p1; p1.x = o[2]; p1.y = o[3];
    f32x2 p2; p2.x = o[4]; p2.y = o[5];
    o2[0] = p0; o2[1] = p1; o2[2] = p2;
}

extern "C" void kernel_launch(void* const* d_in, const int* in_sizes, int n_in,
                              void* d_out, int out_size, void* d_ws, size_t ws_size,
                              hipStream_t stream) {
    const int N = in_sizes[0] / 128;
    const int E = in_sizes[1] / 2;

    const float* x   = (const float*)d_in[0];
    const int*   ei  = (const int*)d_in[1];
    const int*   srcE = ei;
    const int*   dstE = ei + E;
    const float* W1 = (const float*)d_in[3];  const float* b1 = (const float*)d_in[4];
    const float* W2 = (const float*)d_in[5];  const float* b2 = (const float*)d_in[6];
    const float* W3 = (const float*)d_in[7];  const float* b3 = (const float*)d_in[8];
    const float* W4 = (const float*)d_in[9];  const float* b4 = (const float*)d_in[10];
    const float* W5 = (const float*)d_in[11]; const float* b5 = (const float*)d_in[12];
    const float* Wl1 = (const float*)d_in[13]; const float* bl1 = (const float*)d_in[14];
    const float* Wl2 = (const float*)d_in[15]; const float* bl2 = (const float*)d_in[16];
    const float* Wl3 = (const float*)d_in[17]; const float* bl3 = (const float*)d_in[18];
    const float* Wc  = (const float*)d_in[19]; const float* bc  = (const float*)d_in[20];

    // ---- workspace (small persistent arrays) ----
    char* ws = (char*)d_ws;
    size_t off = 0;
    auto take = [&](size_t bytes) -> char* {
        char* p = ws + off;
        off += (bytes + 255) & ~(size_t)255;
        return p;
    };
    int*   row_ptr   = (int*)take((size_t)(N + 1) * 4);
    float* dinv      = (float*)take((size_t)N * 4);
    int*   col_idx   = (int*)take((size_t)E * 4);
    float* h8        = (float*)take((size_t)N * 12 * 4);
    int*   bktBase   = (int*)take((size_t)(NBKT_PAD + 1) * 4);
    int*   bucketTot = (int*)take((size_t)NBKT_PAD * 4);

    // big/transient buffers inside d_out's e-region (dead until edge_kernel overwrites it)
    float* outbuf  = (float*)d_out;
    float* eregion = outbuf + (size_t)E * 6;
    int2* es  = (int2*)eregion;                  // E * 8B (CSR transient)
    int*  Hist = (int*)(es + E);                 // nblk * 1024 * 4B (CSR transient)
    float* bufZ = eregion;                       // up to N*64 (live after CSR build)
    float* bufH = eregion + (size_t)N * 64;      // up to N*64

    int gE = (E + 255) / 256;
    int gAgg = (N + 3) / 4;
    int nblk = (E + CHUNK - 1) / CHUNK;
    int nbkt = (N + 127) >> BKT_SHIFT;
    auto tiles = [&](int rt) { return (N + rt - 1) / rt; };

    // ---- CSR build (no global atomics) ----
    k1_hist<<<nblk, 256, 0, stream>>>(dstE, Hist, E);
    k2a_sum<<<NBKT_PAD / 128, 128, 0, stream>>>(Hist, bucketTot, nblk);
    k2b_scan<<<1, 1024, 0, stream>>>(bucketTot, bktBase, row_ptr + N);
    k2c_rewrite<<<NBKT_PAD / 128, 128, 0, stream>>>(Hist, bktBase, nblk);
    k3_partition<<<nblk, 256, 0, stream>>>(srcE, dstE, Hist, es, E);
    k4_csr<<<nbkt, 256, 0, stream>>>(es, bktBase, col_idx, row_ptr, dinv, N);

    // ---- layer 1: 128 -> 64 ----
    gemm_tiled<128, 64, 0, 16><<<tiles(16), 256, 0, stream>>>(x, W1, nullptr, dinv, bufZ, N);
    aggregate_kernel<64, true, false><<<gAgg, 256, 0, stream>>>(bufZ, row_ptr, col_idx, dinv, b1, bufH, N);
    // ---- layer 2: 64 -> 64 ----
    gemm_tiled<64, 64, 0, 16><<<tiles(16), 256, 0, stream>>>(bufH, W2, nullptr, dinv, bufZ, N);
    aggregate_kernel<64, true, false><<<gAgg, 256, 0, stream>>>(bufZ, row_ptr, col_idx, dinv, b2, bufH, N);
    // ---- layer 3: 64 -> 32 ----
    gemm_tiled<64, 32, 0, 16><<<tiles(16), 256, 0, stream>>>(bufH, W3, nullptr, dinv, bufZ, N);
    aggregate_kernel<32, true, false><<<gAgg, 256, 0, stream>>>(bufZ, row_ptr, col_idx, dinv, b3, bufH, N);
    // ---- layer 4: 32 -> 32, POSTSCALE folds the next layer's dinv pre-multiply ----
    gemm_tiled<32, 32, 0, 16><<<tiles(16), 256, 0, stream>>>(bufH, W4, nullptr, dinv, bufZ, N);
    aggregate_kernel<32, true, true><<<gAgg, 256, 0, stream>>>(bufZ, row_ptr, col_idx, dinv, b4, bufH, N);
    // ---- layer 5 aggregate (input already h4*dinv) ----
    aggregate_kernel<32, false, false><<<gAgg, 256, 0, stream>>>(bufH, row_ptr, col_idx, dinv, nullptr, bufZ, N);
    // ---- fused head: 32->256 tanh, 256->24->18->12 tanh chain ----
    head_kernel<<<tiles(16), 256, 0, stream>>>(bufZ, W5, b5, Wl1, bl1, Wl2, bl2, Wl3, bl3, h8, N);
    // ---- edge output ----
    edge_kernel<<<gE, 256, 0, stream>>>(srcE, dstE, h8, Wc, bc, outbuf, eregion, E);
}

// Round 8
// 999.337 us; speedup vs baseline: 1.4556x; 1.0179x over previous
//
#include <hip/hip_runtime.h>

typedef float f32x4 __attribute__((ext_vector_type(4)));
typedef float f32x2 __attribute__((ext_vector_type(2)));

constexpr int BKT_SHIFT = 7;     // 128 nodes per bucket
constexpr int NBKT_PAD  = 1024;  // padded bucket count (real: ceil(N/128) = 782)
constexpr int CHUNK     = 8192;  // edges per partition block
constexpr int MAXSEG    = 6144;  // LDS staging capacity per bucket (mean ~4096)

// ---- K1: per-chunk bucket histogram (LDS atomics only) ----
__global__ __launch_bounds__(256) void k1_hist(const int* __restrict__ dst,
                                               int* __restrict__ Hist, int ne) {
    __shared__ int lh[NBKT_PAD];
    for (int i = threadIdx.x; i < NBKT_PAD; i += 256) lh[i] = 0;
    __syncthreads();
    int base = blockIdx.x * CHUNK;
    int lim = min(CHUNK, ne - base);
    for (int i = threadIdx.x; i < lim; i += 256)
        atomicAdd(&lh[dst[base + i] >> BKT_SHIFT], 1);
    __syncthreads();
    for (int i = threadIdx.x; i < NBKT_PAD; i += 256)
        Hist[(size_t)blockIdx.x * NBKT_PAD + i] = lh[i];
}

// ---- K2a: per-bucket totals ----
__global__ __launch_bounds__(128) void k2a_sum(const int* __restrict__ Hist,
                                               int* __restrict__ bucketTot, int nblk) {
    int b = blockIdx.x * 128 + threadIdx.x;
    int tot = 0;
    int blk = 0;
    for (; blk + 4 <= nblk; blk += 4)
        tot += Hist[(size_t)blk * NBKT_PAD + b] +
               Hist[(size_t)(blk + 1) * NBKT_PAD + b] +
               Hist[(size_t)(blk + 2) * NBKT_PAD + b] +
               Hist[(size_t)(blk + 3) * NBKT_PAD + b];
    for (; blk < nblk; ++blk) tot += Hist[(size_t)blk * NBKT_PAD + b];
    bucketTot[b] = tot;
}

// ---- K2b: single block scan of 1024 bucket totals -> bktBase ----
__global__ __launch_bounds__(1024) void k2b_scan(const int* __restrict__ bucketTot,
                                                 int* __restrict__ bktBase,
                                                 int* __restrict__ row_ptrN) {
    __shared__ int wsums[16];
    int t = threadIdx.x, wave = t >> 6, lane = t & 63;
    int tot = bucketTot[t];
    int x = tot;
    #pragma unroll
    for (int off = 1; off < 64; off <<= 1) {
        int y = __shfl_up(x, off, 64);
        if (lane >= off) x += y;
    }
    if (lane == 63) wsums[wave] = x;
    __syncthreads();
    if (t < 16) {
        int w = wsums[t];
        #pragma unroll
        for (int off = 1; off < 16; off <<= 1) {
            int y = __shfl_up(w, off, 64);
            if (t >= off) w += y;
        }
        wsums[t] = w;
    }
    __syncthreads();
    int excl = (wave ? wsums[wave - 1] : 0) + (x - tot);
    bktBase[t] = excl;
    if (t == 1023) { bktBase[1024] = excl + tot; *row_ptrN = excl + tot; }
}

// ---- K2c: rewrite Hist to absolute scatter offsets ----
__global__ __launch_bounds__(128) void k2c_rewrite(int* __restrict__ Hist,
                                                   const int* __restrict__ bktBase, int nblk) {
    int b = blockIdx.x * 128 + threadIdx.x;
    int run = bktBase[b];
    for (int blk = 0; blk < nblk; ++blk) {
        size_t idx = (size_t)blk * NBKT_PAD + b;
        int v = Hist[idx];
        Hist[idx] = run;
        run += v;
    }
}

// ---- K3: partition edges into bucket streams ----
__global__ __launch_bounds__(256) void k3_partition(const int* __restrict__ src,
                                                    const int* __restrict__ dst,
                                                    const int* __restrict__ Hist,
                                                    int2* __restrict__ es, int ne) {
    __shared__ int cur[NBKT_PAD];
    for (int i = threadIdx.x; i < NBKT_PAD; i += 256)
        cur[i] = Hist[(size_t)blockIdx.x * NBKT_PAD + i];
    __syncthreads();
    int base = blockIdx.x * CHUNK;
    int lim = min(CHUNK, ne - base);
    for (int i = threadIdx.x; i < lim; i += 256) {
        int d = dst[base + i];
        int s = src[base + i];
        int pos = atomicAdd(&cur[d >> BKT_SHIFT], 1);
        es[pos] = make_int2(s, d);
    }
}

// ---- K4: per-bucket fine CSR + row_ptr + dinv ----
__global__ __launch_bounds__(256) void k4_csr(const int2* __restrict__ es,
                                              const int* __restrict__ bktBase,
                                              int* __restrict__ col_idx,
                                              int* __restrict__ row_ptr,
                                              float* __restrict__ dinv, int n) {
    __shared__ int hist[128];
    __shared__ int rbase[128];
    __shared__ int cur[128];
    __shared__ int stage[MAXSEG];
    int b = blockIdx.x;
    int segs = bktBase[b], sege = bktBase[b + 1];
    int seglen = sege - segs;
    int node0 = b << BKT_SHIFT;
    int nloc = min(128, n - node0);
    int t = threadIdx.x;
    if (t < 128) hist[t] = 0;
    __syncthreads();
    for (int i = t; i < seglen; i += 256)
        atomicAdd(&hist[es[segs + i].y - node0], 1);
    __syncthreads();
    if (t < 64) {
        int a0 = hist[2 * t], a1 = hist[2 * t + 1];
        int pair = a0 + a1;
        int x = pair;
        #pragma unroll
        for (int off = 1; off < 64; off <<= 1) {
            int y = __shfl_up(x, off, 64);
            if (t >= off) x += y;
        }
        int excl = x - pair;
        rbase[2 * t] = excl;       rbase[2 * t + 1] = excl + a0;
        cur[2 * t]   = excl;       cur[2 * t + 1]   = excl + a0;
    }
    __syncthreads();
    if (seglen <= MAXSEG) {
        for (int i = t; i < seglen; i += 256) {
            int2 e = es[segs + i];
            int pos = atomicAdd(&cur[e.y - node0], 1);
            stage[pos] = e.x;
        }
        __syncthreads();
        for (int i = t; i < seglen; i += 256)
            col_idx[segs + i] = stage[i];
    } else {
        for (int i = t; i < seglen; i += 256) {
            int2 e = es[segs + i];
            int pos = atomicAdd(&cur[e.y - node0], 1);
            col_idx[segs + pos] = e.x;
        }
    }
    if (t < nloc) {
        row_ptr[node0 + t] = segs + rbase[t];
        dinv[node0 + t] = 1.0f / sqrtf((float)(hist[t] + 1));
    }
}

// ---------------- gather helpers ----------------
// Per-node neighbor gather-sum: lane layout c = lane%LPR (f32x4 quad), g = lane/LPR
// (neighbor subgroup). Window of 64 indices hoisted; inner loop 4-wide unrolled
// predicated loads -> ~4 outstanding gathers per wave.
template<int F>
__device__ inline f32x4 gather_sum(const float* __restrict__ Z,
                                   const int* __restrict__ col_idx,
                                   int start, int end, int lane, int g, int c) {
    constexpr int LPR = F / 4;
    constexpr int G   = 64 / LPR;
    f32x4 acc = {0.f, 0.f, 0.f, 0.f};
    for (int wb = start; wb < end; wb += 64) {
        int m = min(64, end - wb);
        int iv = (wb + lane < end) ? col_idx[wb + lane] : 0;
        for (int b = 0; b < m; b += 4 * G) {
            #pragma unroll
            for (int j = 0; j < 4; ++j) {
                int bb = b + j * G;
                int s = __shfl(iv, bb + g, 64);
                if (bb + g < m) {
                    acc += *(const f32x4*)(Z + (size_t)s * F + c * 4);
                }
            }
        }
    }
    return acc;
}

template<int LPR>
__device__ inline f32x4 reduce_groups(f32x4 a) {
    #pragma unroll
    for (int off = LPR; off < 64; off <<= 1) {
        a.x += __shfl_xor(a.x, off, 64);
        a.y += __shfl_xor(a.y, off, 64);
        a.z += __shfl_xor(a.z, off, 64);
        a.w += __shfl_xor(a.w, off, 64);
    }
    return a;
}

// ---------------- standalone CSR aggregation ----------------
template<int F, bool FINAL, bool POSTSCALE>
__global__ __launch_bounds__(256) void aggregate_kernel(const float* __restrict__ Z,
        const int* __restrict__ row_ptr, const int* __restrict__ col_idx,
        const float* __restrict__ dinv, const float* __restrict__ bias,
        float* __restrict__ out, int n) {
    constexpr int LPR = F / 4;
    int tid = threadIdx.x;
    int wave = tid >> 6, lane = tid & 63;
    int g = lane / LPR;
    int c = lane - g * LPR;
    int node = blockIdx.x * 4 + wave;
    if (node >= n) return;
    int start = row_ptr[node];
    int end   = row_ptr[node + 1];
    f32x4 acc = gather_sum<F>(Z, col_idx, start, end, lane, g, c);
    acc = reduce_groups<LPR>(acc);
    if (g == 0) {
        const f32x4 sv = *(const f32x4*)(Z + (size_t)node * F + c * 4);
        float di = dinv[node];
        f32x4 r = di * (acc + sv);
        if (FINAL) {
            const f32x4 bv = *(const f32x4*)(bias + c * 4);
            r.x = tanhf(r.x + bv.x);
            r.y = tanhf(r.y + bv.y);
            r.z = tanhf(r.z + bv.z);
            r.w = tanhf(r.w + bv.w);
        }
        if (POSTSCALE) r *= di;
        *(f32x4*)(out + (size_t)node * F + c * 4) = r;
    }
}

// ---------------- fused aggregate + next-layer GEMM ----------------
// Block: 16 nodes. Phase 1: 4 waves aggregate 4 nodes each, h rows (tanh+bias)
// kept in LDS. Phase 2: Z_next[r] = (h[r] @ W) * dinv[r]. h never hits memory.
template<int F, int FOUT>
__global__ __launch_bounds__(256) void agg_gemm_kernel(const float* __restrict__ Z,
        const int* __restrict__ row_ptr, const int* __restrict__ col_idx,
        const float* __restrict__ dinv, const float* __restrict__ aggBias,
        const float* __restrict__ W, float* __restrict__ Y, int n) {
    constexpr int LPR = F / 4;
    __shared__ float Hs[16 * F];
    __shared__ float Wl[F * FOUT];
    int tid = threadIdx.x;
    int wave = tid >> 6, lane = tid & 63;
    int g = lane / LPR;
    int c = lane - g * LPR;
    int row0 = blockIdx.x * 16;
    for (int i = tid; i < F * FOUT / 4; i += 256)
        ((float4*)Wl)[i] = ((const float4*)W)[i];
    #pragma unroll
    for (int i = 0; i < 4; ++i) {
        int node = row0 + wave * 4 + i;
        if (node < n) {
            int start = row_ptr[node];
            int end   = row_ptr[node + 1];
            f32x4 acc = gather_sum<F>(Z, col_idx, start, end, lane, g, c);
            acc = reduce_groups<LPR>(acc);
            if (g == 0) {
                const f32x4 sv = *(const f32x4*)(Z + (size_t)node * F + c * 4);
                float di = dinv[node];
                f32x4 r = di * (acc + sv);
                const f32x4 bv = *(const f32x4*)(aggBias + c * 4);
                r.x = tanhf(r.x + bv.x);
                r.y = tanhf(r.y + bv.y);
                r.z = tanhf(r.z + bv.z);
                r.w = tanhf(r.w + bv.w);
                *(f32x4*)(Hs + (wave * 4 + i) * F + c * 4) = r;
            }
        }
    }
    __syncthreads();
    constexpr int NG  = 256 / FOUT;
    constexpr int RPT = 16 / NG;
    int cc = tid & (FOUT - 1);
    int gg = tid / FOUT;
    int rbase = gg * RPT;
    float acc2[RPT];
    #pragma unroll
    for (int i = 0; i < RPT; ++i) acc2[i] = 0.f;
    #pragma unroll 4
    for (int k = 0; k < F; ++k) {
        float wv = Wl[k * FOUT + cc];
        #pragma unroll
        for (int i = 0; i < RPT; ++i)
            acc2[i] = fmaf(Hs[(rbase + i) * F + k], wv, acc2[i]);
    }
    #pragma unroll
    for (int i = 0; i < RPT; ++i) {
        int r = row0 + rbase + i;
        if (r < n) Y[(size_t)r * FOUT + cc] = acc2[i] * dinv[r];
    }
}

// ---------------- row-tiled dense GEMM (layer 1 only): Y = (X @ W) * dinv ----------------
template<int K, int FOUT, int RT>
__global__ __launch_bounds__(256) void gemm_tiled(const float* __restrict__ X,
        const float* __restrict__ W, const float* __restrict__ dinv,
        float* __restrict__ Y, int nrows) {
    __shared__ float Wl[K * FOUT];
    __shared__ float Xs[RT * K];
    int tid = threadIdx.x;
    for (int i = tid; i < K * FOUT / 4; i += 256)
        ((float4*)Wl)[i] = ((const float4*)W)[i];
    int row0 = blockIdx.x * RT;
    int nr = min(RT, nrows - row0);
    {
        const float4* Xg4 = (const float4*)(X + (size_t)row0 * K);
        float4* Xs4 = (float4*)Xs;
        int lim = nr * (K / 4);
        for (int i = tid; i < lim; i += 256) Xs4[i] = Xg4[i];
    }
    __syncthreads();
    constexpr int NG  = 256 / FOUT;
    constexpr int RPT = RT / NG;
    int c = tid & (FOUT - 1);
    int g = tid / FOUT;
    int rbase = g * RPT;
    float acc[RPT];
    #pragma unroll
    for (int i = 0; i < RPT; ++i) acc[i] = 0.f;
    #pragma unroll 4
    for (int k = 0; k < K; ++k) {
        float wv = Wl[k * FOUT + c];
        #pragma unroll
        for (int i = 0; i < RPT; ++i)
            acc[i] = fmaf(Xs[(rbase + i) * K + k], wv, acc[i]);
    }
    #pragma unroll
    for (int i = 0; i < RPT; ++i) {
        int r = row0 + rbase + i;
        if (r < nrows) Y[(size_t)r * FOUT + c] = acc[i] * dinv[r];
    }
}

// ---------------- fused head: h5=tanh(X@W5+b5); 256->24->18->12 tanh chain ----------------
__global__ __launch_bounds__(256) void head_kernel(const float* __restrict__ X,
        const float* __restrict__ W5, const float* __restrict__ b5,
        const float* __restrict__ Wl1, const float* __restrict__ bl1,
        const float* __restrict__ Wl2, const float* __restrict__ bl2,
        const float* __restrict__ Wl3, const float* __restrict__ bl3,
        float* __restrict__ Y, int nrows) {
    constexpr int RT = 16;
    __shared__ float W5s[32 * 256];   // 32 KB
    __shared__ float W1s[256 * 24];   // 24 KB
    __shared__ float W2s[24 * 18];
    __shared__ float W3s[18 * 12];
    __shared__ float b1s[24], b2s[18], b3s[12];
    __shared__ float Xs[RT * 32];
    __shared__ float H5[RT * 257];    // pad 257: phase-B reads stride-257 -> distinct banks
    __shared__ float H24[RT * 25];
    __shared__ float H18[RT * 19];
    int tid = threadIdx.x;
    for (int i = tid; i < 32 * 256 / 4; i += 256) ((float4*)W5s)[i] = ((const float4*)W5)[i];
    for (int i = tid; i < 256 * 24 / 4; i += 256) ((float4*)W1s)[i] = ((const float4*)Wl1)[i];
    for (int i = tid; i < 432; i += 256) W2s[i] = Wl2[i];
    for (int i = tid; i < 216; i += 256) W3s[i] = Wl3[i];
    if (tid < 24) b1s[tid] = bl1[tid];
    if (tid < 18) b2s[tid] = bl2[tid];
    if (tid < 12) b3s[tid] = bl3[tid];
    float b5r = b5[tid];
    int row0 = blockIdx.x * RT;
    int nr = min(RT, nrows - row0);
    {
        const float4* Xg4 = (const float4*)(X + (size_t)row0 * 32);
        for (int i = tid; i < nr * 8; i += 256) ((float4*)Xs)[i] = Xg4[i];
    }
    __syncthreads();
    {
        float acc[RT];
        #pragma unroll
        for (int r = 0; r < RT; ++r) acc[r] = 0.f;
        #pragma unroll 4
        for (int k = 0; k < 32; ++k) {
            float wv = W5s[k * 256 + tid];
            #pragma unroll
            for (int r = 0; r < RT; ++r)
                acc[r] = fmaf(Xs[r * 32 + k], wv, acc[r]);
        }
        #pragma unroll
        for (int r = 0; r < RT; ++r) H5[r * 257 + tid] = tanhf(acc[r] + b5r);
    }
    __syncthreads();
    for (int o = tid; o < RT * 24; o += 256) {
        int r = o / 24, c = o - r * 24;
        float acc = 0.f;
        #pragma unroll 4
        for (int k = 0; k < 256; ++k) acc = fmaf(H5[r * 257 + k], W1s[k * 24 + c], acc);
        H24[r * 25 + c] = tanhf(acc + b1s[c]);
    }
    __syncthreads();
    for (int o = tid; o < RT * 18; o += 256) {
        int r = o / 18, c = o - r * 18;
        float acc = 0.f;
        #pragma unroll
        for (int k = 0; k < 24; ++k) acc = fmaf(H24[r * 25 + k], W2s[k * 18 + c], acc);
        H18[r * 19 + c] = tanhf(acc + b2s[c]);
    }
    __syncthreads();
    for (int o = tid; o < RT * 12; o += 256) {
        int r = o / 12, c = o - r * 12;
        float acc = 0.f;
        #pragma unroll
        for (int k = 0; k < 18; ++k) acc = fmaf(H18[r * 19 + k], W3s[k * 12 + c], acc);
        if (r < nr) Y[(size_t)(row0 + r) * 12 + c] = tanhf(acc + b3s[c]);
    }
}

// ---------------- final: e = [h[src], h[dst]], out = e @ Wc + bc ----------------
__global__ __launch_bounds__(256) void edge_kernel(const int* __restrict__ src,
        const int* __restrict__ dst, const float* __restrict__ h,
        const float* __restrict__ Wc, const float* __restrict__ bc,
        float* __restrict__ out, float* __restrict__ efeat, int ne) {
    __shared__ float Wl[144];
    __shared__ float bl[6];
    if (threadIdx.x < 144) Wl[threadIdx.x] = Wc[threadIdx.x];
    if (threadIdx.x < 6) bl[threadIdx.x] = bc[threadIdx.x];
    __syncthreads();
    int e = blockIdx.x * 256 + threadIdx.x;
    if (e >= ne) return;
    int s = src[e], d = dst[e];
    const float* hs = h + (size_t)s * 12;
    const float* hd = h + (size_t)d * 12;
    f32x4 v0 = *(const f32x4*)(hs + 0);
    f32x4 v1 = *(const f32x4*)(hs + 4);
    f32x4 v2 = *(const f32x4*)(hs + 8);
    f32x4 v3 = *(const f32x4*)(hd + 0);
    f32x4 v4 = *(const f32x4*)(hd + 4);
    f32x4 v5 = *(const f32x4*)(hd + 8);
    float v[24];
    *(f32x4*)(v + 0)  = v0; *(f32x4*)(v + 4)  = v1; *(f32x4*)(v + 8)  = v2;
    *(f32x4*)(v + 12) = v3; *(f32x4*)(v + 16) = v4; *(f32x4*)(v + 20) = v5;
    f32x4* ef4 = (f32x4*)(efeat + (size_t)e * 24);
    ef4[0] = v0; ef4[1] = v1; ef4[2] = v2; ef4[3] = v3; ef4[4] = v4; ef4[5] = v5;
    float o[6];
    #pragma unroll
    for (int c = 0; c < 6; ++c) {
        float acc = bl[c];
        #pragma unroll
        for (int k = 0; k < 24; ++k) acc = fmaf(v[k], Wl[k * 6 + c], acc);
        o[c] = acc;
    }
    f32x2* o2 = (f32x2*)(out + (size_t)e * 6);
    f32x2 p0; p0.x = o[0]; p0.y = o[1];
    f32x2 p1; p1.x = o[2]; p1.y = o[3];
    f32x2 p2; p2.x = o[4]; p2.y = o[5];
    o2[0] = p0; o2[1] = p1; o2[2] = p2;
}

extern "C" void kernel_launch(void* const* d_in, const int* in_sizes, int n_in,
                              void* d_out, int out_size, void* d_ws, size_t ws_size,
                              hipStream_t stream) {
    const int N = in_sizes[0] / 128;
    const int E = in_sizes[1] / 2;

    const float* x   = (const float*)d_in[0];
    const int*   ei  = (const int*)d_in[1];
    const int*   srcE = ei;
    const int*   dstE = ei + E;
    const float* W1 = (const float*)d_in[3];  const float* b1 = (const float*)d_in[4];
    const float* W2 = (const float*)d_in[5];  const float* b2 = (const float*)d_in[6];
    const float* W3 = (const float*)d_in[7];  const float* b3 = (const float*)d_in[8];
    const float* W4 = (const float*)d_in[9];  const float* b4 = (const float*)d_in[10];
    const float* W5 = (const float*)d_in[11]; const float* b5 = (const float*)d_in[12];
    const float* Wl1 = (const float*)d_in[13]; const float* bl1 = (const float*)d_in[14];
    const float* Wl2 = (const float*)d_in[15]; const float* bl2 = (const float*)d_in[16];
    const float* Wl3 = (const float*)d_in[17]; const float* bl3 = (const float*)d_in[18];
    const float* Wc  = (const float*)d_in[19]; const float* bc  = (const float*)d_in[20];

    // ---- workspace (small persistent arrays) ----
    char* ws = (char*)d_ws;
    size_t off = 0;
    auto take = [&](size_t bytes) -> char* {
        char* p = ws + off;
        off += (bytes + 255) & ~(size_t)255;
        return p;
    };
    int*   row_ptr   = (int*)take((size_t)(N + 1) * 4);
    float* dinv      = (float*)take((size_t)N * 4);
    int*   col_idx   = (int*)take((size_t)E * 4);
    float* h8        = (float*)take((size_t)N * 12 * 4);
    int*   bktBase   = (int*)take((size_t)(NBKT_PAD + 1) * 4);
    int*   bucketTot = (int*)take((size_t)NBKT_PAD * 4);

    // big/transient buffers inside d_out's e-region (dead until edge_kernel overwrites it)
    float* outbuf  = (float*)d_out;
    float* eregion = outbuf + (size_t)E * 6;
    int2* es  = (int2*)eregion;                  // E * 8B (CSR transient)
    int*  Hist = (int*)(es + E);                 // nblk * 1024 * 4B (CSR transient)
    float* bufZ = eregion;                       // up to N*64 (live after CSR build)
    float* bufH = eregion + (size_t)N * 64;      // up to N*64

    int gE = (E + 255) / 256;
    int gAgg = (N + 3) / 4;
    int g16  = (N + 15) / 16;
    int nblk = (E + CHUNK - 1) / CHUNK;
    int nbkt = (N + 127) >> BKT_SHIFT;

    // ---- CSR build (no global atomics) ----
    k1_hist<<<nblk, 256, 0, stream>>>(dstE, Hist, E);
    k2a_sum<<<NBKT_PAD / 128, 128, 0, stream>>>(Hist, bucketTot, nblk);
    k2b_scan<<<1, 1024, 0, stream>>>(bucketTot, bktBase, row_ptr + N);
    k2c_rewrite<<<NBKT_PAD / 128, 128, 0, stream>>>(Hist, bktBase, nblk);
    k3_partition<<<nblk, 256, 0, stream>>>(srcE, dstE, Hist, es, E);
    k4_csr<<<nbkt, 256, 0, stream>>>(es, bktBase, col_idx, row_ptr, dinv, N);

    // ---- layer 1 GEMM: Z1 = (x @ W1) * dinv ----
    gemm_tiled<128, 64, 16><<<g16, 256, 0, stream>>>(x, W1, dinv, bufZ, N);
    // ---- fused: h1 = tanh(agg(Z1)+b1);  Z2 = (h1 @ W2) * dinv ----
    agg_gemm_kernel<64, 64><<<g16, 256, 0, stream>>>(bufZ, row_ptr, col_idx, dinv, b1, W2, bufH, N);
    // ---- fused: h2 = tanh(agg(Z2)+b2);  Z3 = (h2 @ W3) * dinv ----
    agg_gemm_kernel<64, 32><<<g16, 256, 0, stream>>>(bufH, row_ptr, col_idx, dinv, b2, W3, bufZ, N);
    // ---- fused: h3 = tanh(agg(Z3)+b3);  Z4 = (h3 @ W4) * dinv ----
    agg_gemm_kernel<32, 32><<<g16, 256, 0, stream>>>(bufZ, row_ptr, col_idx, dinv, b3, W4, bufH, N);
    // ---- h4' = tanh(agg(Z4)+b4) * dinv (postscale for layer-5 aggregate-first) ----
    aggregate_kernel<32, true, true><<<gAgg, 256, 0, stream>>>(bufH, row_ptr, col_idx, dinv, b4, bufZ, N);
    // ---- g = dinv * (sum h4' + self) ----
    aggregate_kernel<32, false, false><<<gAgg, 256, 0, stream>>>(bufZ, row_ptr, col_idx, dinv, nullptr, bufH, N);
    // ---- fused head: 32->256 tanh, 256->24->18->12 tanh chain ----
    head_kernel<<<g16, 256, 0, stream>>>(bufH, W5, b5, Wl1, bl1, Wl2, bl2, Wl3, bl3, h8, N);
    // ---- edge output ----
    edge_kernel<<<gE, 256, 0, stream>>>(srcE, dstE, h8, Wc, bc, outbuf, eregion, E);
}

// Round 9
// 913.299 us; speedup vs baseline: 1.5927x; 1.0942x over previous
//
#include <hip/hip_runtime.h>

typedef float f32x4 __attribute__((ext_vector_type(4)));
typedef float f32x2 __attribute__((ext_vector_type(2)));

constexpr int BKT_SHIFT = 7;     // 128 nodes per bucket
constexpr int NBKT_PAD  = 1024;  // padded bucket count (real: ceil(N/128) = 782)
constexpr int CHUNK     = 16384; // edges per partition block (128B per-bucket runs in k3)
constexpr int MAXSEG    = 6144;  // LDS staging capacity per bucket (mean ~4096)

// ---- K1: per-chunk bucket histogram (LDS atomics only) ----
__global__ __launch_bounds__(256) void k1_hist(const int* __restrict__ dst,
                                               int* __restrict__ Hist, int ne) {
    __shared__ int lh[NBKT_PAD];
    for (int i = threadIdx.x; i < NBKT_PAD; i += 256) lh[i] = 0;
    __syncthreads();
    int base = blockIdx.x * CHUNK;
    int lim = min(CHUNK, ne - base);
    for (int i = threadIdx.x; i < lim; i += 256)
        atomicAdd(&lh[dst[base + i] >> BKT_SHIFT], 1);
    __syncthreads();
    for (int i = threadIdx.x; i < NBKT_PAD; i += 256)
        Hist[(size_t)blockIdx.x * NBKT_PAD + i] = lh[i];
}

// ---- K2a: per-bucket totals ----
__global__ __launch_bounds__(128) void k2a_sum(const int* __restrict__ Hist,
                                               int* __restrict__ bucketTot, int nblk) {
    int b = blockIdx.x * 128 + threadIdx.x;
    int tot = 0;
    int blk = 0;
    for (; blk + 4 <= nblk; blk += 4)
        tot += Hist[(size_t)blk * NBKT_PAD + b] +
               Hist[(size_t)(blk + 1) * NBKT_PAD + b] +
               Hist[(size_t)(blk + 2) * NBKT_PAD + b] +
               Hist[(size_t)(blk + 3) * NBKT_PAD + b];
    for (; blk < nblk; ++blk) tot += Hist[(size_t)blk * NBKT_PAD + b];
    bucketTot[b] = tot;
}

// ---- K2b: single block scan of 1024 bucket totals -> bktBase ----
__global__ __launch_bounds__(1024) void k2b_scan(const int* __restrict__ bucketTot,
                                                 int* __restrict__ bktBase,
                                                 int* __restrict__ row_ptrN) {
    __shared__ int wsums[16];
    int t = threadIdx.x, wave = t >> 6, lane = t & 63;
    int tot = bucketTot[t];
    int x = tot;
    #pragma unroll
    for (int off = 1; off < 64; off <<= 1) {
        int y = __shfl_up(x, off, 64);
        if (lane >= off) x += y;
    }
    if (lane == 63) wsums[wave] = x;
    __syncthreads();
    if (t < 16) {
        int w = wsums[t];
        #pragma unroll
        for (int off = 1; off < 16; off <<= 1) {
            int y = __shfl_up(w, off, 64);
            if (t >= off) w += y;
        }
        wsums[t] = w;
    }
    __syncthreads();
    int excl = (wave ? wsums[wave - 1] : 0) + (x - tot);
    bktBase[t] = excl;
    if (t == 1023) { bktBase[1024] = excl + tot; *row_ptrN = excl + tot; }
}

// ---- K2c: rewrite Hist to absolute scatter offsets ----
__global__ __launch_bounds__(128) void k2c_rewrite(int* __restrict__ Hist,
                                                   const int* __restrict__ bktBase, int nblk) {
    int b = blockIdx.x * 128 + threadIdx.x;
    int run = bktBase[b];
    for (int blk = 0; blk < nblk; ++blk) {
        size_t idx = (size_t)blk * NBKT_PAD + b;
        int v = Hist[idx];
        Hist[idx] = run;
        run += v;
    }
}

// ---- K3: partition edges into bucket streams ----
__global__ __launch_bounds__(256) void k3_partition(const int* __restrict__ src,
                                                    const int* __restrict__ dst,
                                                    const int* __restrict__ Hist,
                                                    int2* __restrict__ es, int ne) {
    __shared__ int cur[NBKT_PAD];
    for (int i = threadIdx.x; i < NBKT_PAD; i += 256)
        cur[i] = Hist[(size_t)blockIdx.x * NBKT_PAD + i];
    __syncthreads();
    int base = blockIdx.x * CHUNK;
    int lim = min(CHUNK, ne - base);
    for (int i = threadIdx.x; i < lim; i += 256) {
        int d = dst[base + i];
        int s = src[base + i];
        int pos = atomicAdd(&cur[d >> BKT_SHIFT], 1);
        es[pos] = make_int2(s, d);
    }
}

// ---- K4: per-bucket fine CSR + row_ptr + dinv ----
__global__ __launch_bounds__(256) void k4_csr(const int2* __restrict__ es,
                                              const int* __restrict__ bktBase,
                                              int* __restrict__ col_idx,
                                              int* __restrict__ row_ptr,
                                              float* __restrict__ dinv, int n) {
    __shared__ int hist[128];
    __shared__ int rbase[128];
    __shared__ int cur[128];
    __shared__ int stage[MAXSEG];
    int b = blockIdx.x;
    int segs = bktBase[b], sege = bktBase[b + 1];
    int seglen = sege - segs;
    int node0 = b << BKT_SHIFT;
    int nloc = min(128, n - node0);
    int t = threadIdx.x;
    if (t < 128) hist[t] = 0;
    __syncthreads();
    for (int i = t; i < seglen; i += 256)
        atomicAdd(&hist[es[segs + i].y - node0], 1);
    __syncthreads();
    if (t < 64) {
        int a0 = hist[2 * t], a1 = hist[2 * t + 1];
        int pair = a0 + a1;
        int x = pair;
        #pragma unroll
        for (int off = 1; off < 64; off <<= 1) {
            int y = __shfl_up(x, off, 64);
            if (t >= off) x += y;
        }
        int excl = x - pair;
        rbase[2 * t] = excl;       rbase[2 * t + 1] = excl + a0;
        cur[2 * t]   = excl;       cur[2 * t + 1]   = excl + a0;
    }
    __syncthreads();
    if (seglen <= MAXSEG) {
        for (int i = t; i < seglen; i += 256) {
            int2 e = es[segs + i];
            int pos = atomicAdd(&cur[e.y - node0], 1);
            stage[pos] = e.x;
        }
        __syncthreads();
        for (int i = t; i < seglen; i += 256)
            col_idx[segs + i] = stage[i];
    } else {
        for (int i = t; i < seglen; i += 256) {
            int2 e = es[segs + i];
            int pos = atomicAdd(&cur[e.y - node0], 1);
            col_idx[segs + pos] = e.x;
        }
    }
    if (t < nloc) {
        row_ptr[node0 + t] = segs + rbase[t];
        dinv[node0 + t] = 1.0f / sqrtf((float)(hist[t] + 1));
    }
}

// ---------------- gather helpers ----------------
// Two-phase staged gather: per chunk, ISSUE CH predicated row loads into v[]
// (no dependent consumer between them -> CH loads in flight), then accumulate.
// Lane layout: c = lane%LPR (f32x4 quad), g = lane/LPR (neighbor subgroup).
template<int F>
__device__ inline f32x4 gather_sum(const float* __restrict__ Z,
                                   const int* __restrict__ col_idx,
                                   int start, int end, int lane, int g, int c) {
    constexpr int LPR = F / 4;          // 16 (F=64) or 8 (F=32)
    constexpr int G   = 64 / LPR;       // 4 or 8 neighbors per load instr
    constexpr int CH  = (G == 4) ? 8 : 4;  // staged loads per chunk
    f32x4 acc = {0.f, 0.f, 0.f, 0.f};
    for (int wb = start; wb < end; wb += 64) {
        int m = end - wb;
        if (m > 64) m = 64;
        int iv = (lane < m) ? col_idx[wb + lane] : 0;
        int ng = (m + G - 1) / G;       // groups in this window (<= 64/G)
        for (int base = 0; base < ng; base += CH) {
            f32x4 v[CH];
            #pragma unroll
            for (int j = 0; j < CH; ++j) {
                int grp = base + j;
                int nb = grp * G + g;
                int s = __shfl(iv, nb & 63, 64);
                bool p = (grp < ng) && (nb < m);
                const f32x4* ptr = (const f32x4*)(Z + (size_t)s * F + c * 4);
                v[j] = p ? *ptr : (f32x4){0.f, 0.f, 0.f, 0.f};
            }
            #pragma unroll
            for (int j = 0; j < CH; ++j) acc += v[j];
        }
    }
    return acc;
}

template<int LPR>
__device__ inline f32x4 reduce_groups(f32x4 a) {
    #pragma unroll
    for (int off = LPR; off < 64; off <<= 1) {
        a.x += __shfl_xor(a.x, off, 64);
        a.y += __shfl_xor(a.y, off, 64);
        a.z += __shfl_xor(a.z, off, 64);
        a.w += __shfl_xor(a.w, off, 64);
    }
    return a;
}

// ---------------- standalone CSR aggregation ----------------
template<int F, bool FINAL, bool POSTSCALE>
__global__ __launch_bounds__(256) void aggregate_kernel(const float* __restrict__ Z,
        const int* __restrict__ row_ptr, const int* __restrict__ col_idx,
        const float* __restrict__ dinv, const float* __restrict__ bias,
        float* __restrict__ out, int n) {
    constexpr int LPR = F / 4;
    int tid = threadIdx.x;
    int wave = tid >> 6, lane = tid & 63;
    int g = lane / LPR;
    int c = lane - g * LPR;
    int node = blockIdx.x * 4 + wave;
    if (node >= n) return;
    int start = row_ptr[node];
    int end   = row_ptr[node + 1];
    f32x4 acc = gather_sum<F>(Z, col_idx, start, end, lane, g, c);
    acc = reduce_groups<LPR>(acc);
    if (g == 0) {
        const f32x4 sv = *(const f32x4*)(Z + (size_t)node * F + c * 4);
        float di = dinv[node];
        f32x4 r = di * (acc + sv);
        if (FINAL) {
            const f32x4 bv = *(const f32x4*)(bias + c * 4);
            r.x = tanhf(r.x + bv.x);
            r.y = tanhf(r.y + bv.y);
            r.z = tanhf(r.z + bv.z);
            r.w = tanhf(r.w + bv.w);
        }
        if (POSTSCALE) r *= di;
        *(f32x4*)(out + (size_t)node * F + c * 4) = r;
    }
}

// ---------------- fused aggregate + next-layer GEMM ----------------
template<int F, int FOUT>
__global__ __launch_bounds__(256) void agg_gemm_kernel(const float* __restrict__ Z,
        const int* __restrict__ row_ptr, const int* __restrict__ col_idx,
        const float* __restrict__ dinv, const float* __restrict__ aggBias,
        const float* __restrict__ W, float* __restrict__ Y, int n) {
    constexpr int LPR = F / 4;
    __shared__ float Hs[16 * F];
    __shared__ float Wl[F * FOUT];
    int tid = threadIdx.x;
    int wave = tid >> 6, lane = tid & 63;
    int g = lane / LPR;
    int c = lane - g * LPR;
    int row0 = blockIdx.x * 16;
    for (int i = tid; i < F * FOUT / 4; i += 256)
        ((float4*)Wl)[i] = ((const float4*)W)[i];
    #pragma unroll
    for (int i = 0; i < 4; ++i) {
        int node = row0 + wave * 4 + i;
        if (node < n) {
            int start = row_ptr[node];
            int end   = row_ptr[node + 1];
            f32x4 acc = gather_sum<F>(Z, col_idx, start, end, lane, g, c);
            acc = reduce_groups<LPR>(acc);
            if (g == 0) {
                const f32x4 sv = *(const f32x4*)(Z + (size_t)node * F + c * 4);
                float di = dinv[node];
                f32x4 r = di * (acc + sv);
                const f32x4 bv = *(const f32x4*)(aggBias + c * 4);
                r.x = tanhf(r.x + bv.x);
                r.y = tanhf(r.y + bv.y);
                r.z = tanhf(r.z + bv.z);
                r.w = tanhf(r.w + bv.w);
                *(f32x4*)(Hs + (wave * 4 + i) * F + c * 4) = r;
            }
        }
    }
    __syncthreads();
    constexpr int NG  = 256 / FOUT;
    constexpr int RPT = 16 / NG;
    int cc = tid & (FOUT - 1);
    int gg = tid / FOUT;
    int rbase = gg * RPT;
    float acc2[RPT];
    #pragma unroll
    for (int i = 0; i < RPT; ++i) acc2[i] = 0.f;
    #pragma unroll 4
    for (int k = 0; k < F; ++k) {
        float wv = Wl[k * FOUT + cc];
        #pragma unroll
        for (int i = 0; i < RPT; ++i)
            acc2[i] = fmaf(Hs[(rbase + i) * F + k], wv, acc2[i]);
    }
    #pragma unroll
    for (int i = 0; i < RPT; ++i) {
        int r = row0 + rbase + i;
        if (r < n) Y[(size_t)r * FOUT + cc] = acc2[i] * dinv[r];
    }
}

// ---------------- row-tiled dense GEMM (layer 1 only): Y = (X @ W) * dinv ----------------
template<int K, int FOUT, int RT>
__global__ __launch_bounds__(256) void gemm_tiled(const float* __restrict__ X,
        const float* __restrict__ W, const float* __restrict__ dinv,
        float* __restrict__ Y, int nrows) {
    __shared__ float Wl[K * FOUT];
    __shared__ float Xs[RT * K];
    int tid = threadIdx.x;
    for (int i = tid; i < K * FOUT / 4; i += 256)
        ((float4*)Wl)[i] = ((const float4*)W)[i];
    int row0 = blockIdx.x * RT;
    int nr = min(RT, nrows - row0);
    {
        const float4* Xg4 = (const float4*)(X + (size_t)row0 * K);
        float4* Xs4 = (float4*)Xs;
        int lim = nr * (K / 4);
        for (int i = tid; i < lim; i += 256) Xs4[i] = Xg4[i];
    }
    __syncthreads();
    constexpr int NG  = 256 / FOUT;
    constexpr int RPT = RT / NG;
    int c = tid & (FOUT - 1);
    int g = tid / FOUT;
    int rbase = g * RPT;
    float acc[RPT];
    #pragma unroll
    for (int i = 0; i < RPT; ++i) acc[i] = 0.f;
    #pragma unroll 4
    for (int k = 0; k < K; ++k) {
        float wv = Wl[k * FOUT + c];
        #pragma unroll
        for (int i = 0; i < RPT; ++i)
            acc[i] = fmaf(Xs[(rbase + i) * K + k], wv, acc[i]);
    }
    #pragma unroll
    for (int i = 0; i < RPT; ++i) {
        int r = row0 + rbase + i;
        if (r < nrows) Y[(size_t)r * FOUT + c] = acc[i] * dinv[r];
    }
}

// ---------------- fused head: h5=tanh(X@W5+b5); 256->24->18->12 tanh chain ----------------
// Output rows padded to 16 floats (64B slots) for single-line edge gathers.
__global__ __launch_bounds__(256) void head_kernel(const float* __restrict__ X,
        const float* __restrict__ W5, const float* __restrict__ b5,
        const float* __restrict__ Wl1, const float* __restrict__ bl1,
        const float* __restrict__ Wl2, const float* __restrict__ bl2,
        const float* __restrict__ Wl3, const float* __restrict__ bl3,
        float* __restrict__ Y, int nrows) {
    constexpr int RT = 16;
    __shared__ float W5s[32 * 256];   // 32 KB
    __shared__ float W1s[256 * 24];   // 24 KB
    __shared__ float W2s[24 * 18];
    __shared__ float W3s[18 * 12];
    __shared__ float b1s[24], b2s[18], b3s[12];
    __shared__ float Xs[RT * 32];
    __shared__ float H5[RT * 257];    // pad 257: phase-B reads stride-257 -> distinct banks
    __shared__ float H24[RT * 25];
    __shared__ float H18[RT * 19];
    int tid = threadIdx.x;
    for (int i = tid; i < 32 * 256 / 4; i += 256) ((float4*)W5s)[i] = ((const float4*)W5)[i];
    for (int i = tid; i < 256 * 24 / 4; i += 256) ((float4*)W1s)[i] = ((const float4*)Wl1)[i];
    for (int i = tid; i < 432; i += 256) W2s[i] = Wl2[i];
    for (int i = tid; i < 216; i += 256) W3s[i] = Wl3[i];
    if (tid < 24) b1s[tid] = bl1[tid];
    if (tid < 18) b2s[tid] = bl2[tid];
    if (tid < 12) b3s[tid] = bl3[tid];
    float b5r = b5[tid];
    int row0 = blockIdx.x * RT;
    int nr = min(RT, nrows - row0);
    {
        const float4* Xg4 = (const float4*)(X + (size_t)row0 * 32);
        for (int i = tid; i < nr * 8; i += 256) ((float4*)Xs)[i] = Xg4[i];
    }
    __syncthreads();
    {
        float acc[RT];
        #pragma unroll
        for (int r = 0; r < RT; ++r) acc[r] = 0.f;
        #pragma unroll 4
        for (int k = 0; k < 32; ++k) {
            float wv = W5s[k * 256 + tid];
            #pragma unroll
            for (int r = 0; r < RT; ++r)
                acc[r] = fmaf(Xs[r * 32 + k], wv, acc[r]);
        }
        #pragma unroll
        for (int r = 0; r < RT; ++r) H5[r * 257 + tid] = tanhf(acc[r] + b5r);
    }
    __syncthreads();
    for (int o = tid; o < RT * 24; o += 256) {
        int r = o / 24, c = o - r * 24;
        float acc = 0.f;
        #pragma unroll 4
        for (int k = 0; k < 256; ++k) acc = fmaf(H5[r * 257 + k], W1s[k * 24 + c], acc);
        H24[r * 25 + c] = tanhf(acc + b1s[c]);
    }
    __syncthreads();
    for (int o = tid; o < RT * 18; o += 256) {
        int r = o / 18, c = o - r * 18;
        float acc = 0.f;
        #pragma unroll
        for (int k = 0; k < 24; ++k) acc = fmaf(H24[r * 25 + k], W2s[k * 18 + c], acc);
        H18[r * 19 + c] = tanhf(acc + b2s[c]);
    }
    __syncthreads();
    for (int o = tid; o < RT * 12; o += 256) {
        int r = o / 12, c = o - r * 12;
        float acc = 0.f;
        #pragma unroll
        for (int k = 0; k < 18; ++k) acc = fmaf(H18[r * 19 + k], W3s[k * 12 + c], acc);
        if (r < nr) Y[(size_t)(row0 + r) * 16 + c] = tanhf(acc + b3s[c]);  // stride 16
    }
}

// ---------------- final: e = [h[src], h[dst]], out = e @ Wc + bc ----------------
// h rows padded to 16 floats (64B aligned slots -> 1-line gathers).
__global__ __launch_bounds__(256) void edge_kernel(const int* __restrict__ src,
        const int* __restrict__ dst, const float* __restrict__ h,
        const float* __restrict__ Wc, const float* __restrict__ bc,
        float* __restrict__ out, float* __restrict__ efeat, int ne) {
    __shared__ float Wl[144];
    __shared__ float bl[6];
    if (threadIdx.x < 144) Wl[threadIdx.x] = Wc[threadIdx.x];
    if (threadIdx.x < 6) bl[threadIdx.x] = bc[threadIdx.x];
    __syncthreads();
    int e = blockIdx.x * 256 + threadIdx.x;
    if (e >= ne) return;
    int s = src[e], d = dst[e];
    const float* hs = h + (size_t)s * 16;
    const float* hd = h + (size_t)d * 16;
    f32x4 v0 = *(const f32x4*)(hs + 0);
    f32x4 v1 = *(const f32x4*)(hs + 4);
    f32x4 v2 = *(const f32x4*)(hs + 8);
    f32x4 v3 = *(const f32x4*)(hd + 0);
    f32x4 v4 = *(const f32x4*)(hd + 4);
    f32x4 v5 = *(const f32x4*)(hd + 8);
    float v[24];
    *(f32x4*)(v + 0)  = v0; *(f32x4*)(v + 4)  = v1; *(f32x4*)(v + 8)  = v2;
    *(f32x4*)(v + 12) = v3; *(f32x4*)(v + 16) = v4; *(f32x4*)(v + 20) = v5;
    f32x4* ef4 = (f32x4*)(efeat + (size_t)e * 24);
    ef4[0] = v0; ef4[1] = v1; ef4[2] = v2; ef4[3] = v3; ef4[4] = v4; ef4[5] = v5;
    float o[6];
    #pragma unroll
    for (int c = 0; c < 6; ++c) {
        float acc = bl[c];
        #pragma unroll
        for (int k = 0; k < 24; ++k) acc = fmaf(v[k], Wl[k * 6 + c], acc);
        o[c] = acc;
    }
    f32x2* o2 = (f32x2*)(out + (size_t)e * 6);
    f32x2 p0; p0.x = o[0]; p0.y = o[1];
    f32x2 p1; p1.x = o[2]; p1.y = o[3];
    f32x2 p2; p2.x = o[4]; p2.y = o[5];
    o2[0] = p0; o2[1] = p1; o2[2] = p2;
}

extern "C" void kernel_launch(void* const* d_in, const int* in_sizes, int n_in,
                              void* d_out, int out_size, void* d_ws, size_t ws_size,
                              hipStream_t stream) {
    const int N = in_sizes[0] / 128;
    const int E = in_sizes[1] / 2;

    const float* x   = (const float*)d_in[0];
    const int*   ei  = (const int*)d_in[1];
    const int*   srcE = ei;
    const int*   dstE = ei + E;
    const float* W1 = (const float*)d_in[3];  const float* b1 = (const float*)d_in[4];
    const float* W2 = (const float*)d_in[5];  const float* b2 = (const float*)d_in[6];
    const float* W3 = (const float*)d_in[7];  const float* b3 = (const float*)d_in[8];
    const float* W4 = (const float*)d_in[9];  const float* b4 = (const float*)d_in[10];
    const float* W5 = (const float*)d_in[11]; const float* b5 = (const float*)d_in[12];
    const float* Wl1 = (const float*)d_in[13]; const float* bl1 = (const float*)d_in[14];
    const float* Wl2 = (const float*)d_in[15]; const float* bl2 = (const float*)d_in[16];
    const float* Wl3 = (const float*)d_in[17]; const float* bl3 = (const float*)d_in[18];
    const float* Wc  = (const float*)d_in[19]; const float* bc  = (const float*)d_in[20];

    // ---- workspace (small persistent arrays) ----
    char* ws = (char*)d_ws;
    size_t off = 0;
    auto take = [&](size_t bytes) -> char* {
        char* p = ws + off;
        off += (bytes + 255) & ~(size_t)255;
        return p;
    };
    int*   row_ptr   = (int*)take((size_t)(N + 1) * 4);
    float* dinv      = (float*)take((size_t)N * 4);
    int*   col_idx   = (int*)take((size_t)E * 4);
    float* h8        = (float*)take((size_t)N * 16 * 4);   // padded to 16 floats/row
    int*   bktBase   = (int*)take((size_t)(NBKT_PAD + 1) * 4);
    int*   bucketTot = (int*)take((size_t)NBKT_PAD * 4);

    // big/transient buffers inside d_out's e-region (dead until edge_kernel overwrites it)
    float* outbuf  = (float*)d_out;
    float* eregion = outbuf + (size_t)E * 6;
    int2* es  = (int2*)eregion;                  // E * 8B (CSR transient)
    int*  Hist = (int*)(es + E);                 // nblk * 1024 * 4B (CSR transient)
    float* bufZ = eregion;                       // up to N*64 (live after CSR build)
    float* bufH = eregion + (size_t)N * 64;      // up to N*64

    int gE = (E + 255) / 256;
    int gAgg = (N + 3) / 4;
    int g16  = (N + 15) / 16;
    int nblk = (E + CHUNK - 1) / CHUNK;
    int nbkt = (N + 127) >> BKT_SHIFT;

    // ---- CSR build (no global atomics) ----
    k1_hist<<<nblk, 256, 0, stream>>>(dstE, Hist, E);
    k2a_sum<<<NBKT_PAD / 128, 128, 0, stream>>>(Hist, bucketTot, nblk);
    k2b_scan<<<1, 1024, 0, stream>>>(bucketTot, bktBase, row_ptr + N);
    k2c_rewrite<<<NBKT_PAD / 128, 128, 0, stream>>>(Hist, bktBase, nblk);
    k3_partition<<<nblk, 256, 0, stream>>>(srcE, dstE, Hist, es, E);
    k4_csr<<<nbkt, 256, 0, stream>>>(es, bktBase, col_idx, row_ptr, dinv, N);

    // ---- layer 1 GEMM: Z1 = (x @ W1) * dinv ----
    gemm_tiled<128, 64, 16><<<g16, 256, 0, stream>>>(x, W1, dinv, bufZ, N);
    // ---- fused: h1 = tanh(agg(Z1)+b1);  Z2 = (h1 @ W2) * dinv ----
    agg_gemm_kernel<64, 64><<<g16, 256, 0, stream>>>(bufZ, row_ptr, col_idx, dinv, b1, W2, bufH, N);
    // ---- fused: h2 = tanh(agg(Z2)+b2);  Z3 = (h2 @ W3) * dinv ----
    agg_gemm_kernel<64, 32><<<g16, 256, 0, stream>>>(bufH, row_ptr, col_idx, dinv, b2, W3, bufZ, N);
    // ---- fused: h3 = tanh(agg(Z3)+b3);  Z4 = (h3 @ W4) * dinv ----
    agg_gemm_kernel<32, 32><<<g16, 256, 0, stream>>>(bufZ, row_ptr, col_idx, dinv, b3, W4, bufH, N);
    // ---- h4' = tanh(agg(Z4)+b4) * dinv (postscale for layer-5 aggregate-first) ----
    aggregate_kernel<32, true, true><<<gAgg, 256, 0, stream>>>(bufH, row_ptr, col_idx, dinv, b4, bufZ, N);
    // ---- g = dinv * (agg(h4') + self) ----
    aggregate_kernel<32, false, false><<<gAgg, 256, 0, stream>>>(bufZ, row_ptr, col_idx, dinv, nullptr, bufH, N);
    // ---- fused head: 32->256 tanh, 256->24->18->12 tanh chain (h8 stride 16) ----
    head_kernel<<<g16, 256, 0, stream>>>(bufH, W5, b5, Wl1, bl1, Wl2, bl2, Wl3, bl3, h8, N);
    // ---- edge output ----
    edge_kernel<<<gE, 256, 0, stream>>>(srcE, dstE, h8, Wc, bc, outbuf, eregion, E);
}